// Round 1
// 242.696 us; speedup vs baseline: 1.3351x; 1.3351x over previous
//
#include <hip/hip_runtime.h>

typedef _Float16 half8_t __attribute__((ext_vector_type(8)));
typedef float    f32x4_t __attribute__((ext_vector_type(4)));

#define OUT_HALF 1351680   // 4096*330
#define NDE 330

// ws layout (bytes)
#define OFF_X16    0u
#define OFF_MEANT  524288u
#define OFF_LOGVT  5931008u
#define OFF_W1H    11337728u   // 330*8192 halves  (W1 frags, b1 folded)
#define OFF_W3H    16744448u   // 330*2048 halves  (W3 frags)
#define OFF_W2H    18096128u   // 330*16384 halves (W2 sigma-permuted)
#define WS_PACKED_BYTES 28909568u

__device__ __forceinline__ float fast_silu(float x) {
    float e = __builtin_amdgcn_exp2f(x * -1.44269504f);
    return x * __builtin_amdgcn_rcpf(1.0f + e);
}

__device__ __forceinline__ float fast_softplus(float x) {
    float e = __builtin_amdgcn_exp2f(x * 1.44269504f);
    return __builtin_amdgcn_logf(1.0f + e) * 0.69314718f;
}

// ---- x prep only (fallback path)
__global__ __launch_bounds__(256) void prep_x_kernel(const float* __restrict__ x,
                                                     _Float16* __restrict__ x16) {
    int idx = blockIdx.x * 256 + threadIdx.x;
    if (idx >= 4096 * 64) return;
    int b = idx >> 6, cc = idx & 63;
    float v = (cc < 40) ? x[b * 40 + cc] : (cc == 40 ? 1.0f : 0.0f);
    x16[idx] = (_Float16)v;
}

// ---- combined prep: x16 + W1/W3 fragment pack + W2 sigma pack (packed path)
__global__ __launch_bounds__(256) void prep_all_kernel(
    const float* __restrict__ x,
    const float* __restrict__ W1, const float* __restrict__ b1,
    const float* __restrict__ W2, const float* __restrict__ W3,
    _Float16* __restrict__ x16, _Float16* __restrict__ w1h,
    _Float16* __restrict__ w2h, _Float16* __restrict__ w3h)
{
    const int blk = blockIdx.x;
    const int tid = threadIdx.x;
    if (blk < 1024) {
        int idx = blk * 256 + tid;
        int b = idx >> 6, cc = idx & 63;
        float v = (cc < 40) ? x[b * 40 + cc] : (cc == 40 ? 1.0f : 0.0f);
        x16[idx] = (_Float16)v;
        return;
    }
    if (blk < 1024 + NDE) {
        const int de = blk - 1024;
        const float* W1g = W1 + (size_t)de * (128 * 40);
        const float* b1g = b1 + (size_t)de * 128;
        const float* W3g = W3 + (size_t)de * 256;
        for (int s = tid; s < 1024; s += 256) {
            int ht = s >> 7, rem = s & 127, kf = rem >> 6, lane = rem & 63;
            int c = lane & 15, q = lane >> 4, h = ht * 16 + c;
            union { _Float16 hh[8]; half8_t v; } u;
            if (kf == 0) {
                f32x4_t a  = *(const f32x4_t*)&W1g[h * 40 + q * 8];
                f32x4_t bb = *(const f32x4_t*)&W1g[h * 40 + q * 8 + 4];
                #pragma unroll
                for (int r = 0; r < 4; r++) { u.hh[r] = (_Float16)a[r]; u.hh[4 + r] = (_Float16)bb[r]; }
            } else {
                #pragma unroll
                for (int r = 0; r < 8; r++) u.hh[r] = (_Float16)0.0f;
                if (q == 0) {
                    f32x4_t a  = *(const f32x4_t*)&W1g[h * 40 + 32];
                    f32x4_t bb = *(const f32x4_t*)&W1g[h * 40 + 36];
                    #pragma unroll
                    for (int r = 0; r < 4; r++) { u.hh[r] = (_Float16)a[r]; u.hh[4 + r] = (_Float16)bb[r]; }
                } else if (q == 1) {
                    u.hh[0] = (_Float16)b1g[h];
                }
            }
            *(half8_t*)&w1h[(size_t)de * 8192 + (ht * 2 + kf) * 512 + lane * 8] = u.v;
        }
        if (tid < 256) {
            int kf = tid >> 6, lane = tid & 63, c = lane & 15, q = lane >> 4;
            union { _Float16 hh[8]; half8_t v; } u;
            #pragma unroll
            for (int r = 0; r < 8; r++) u.hh[r] = (_Float16)0.0f;
            if (c < 2) {
                #pragma unroll
                for (int r = 0; r < 4; r++) {
                    u.hh[r]     = (_Float16)W3g[c * 128 + kf * 32 + q * 4 + r];
                    u.hh[4 + r] = (_Float16)W3g[c * 128 + kf * 32 + 16 + q * 4 + r];
                }
            }
            *(half8_t*)&w3h[(size_t)de * 2048 + kf * 512 + lane * 8] = u.v;
        }
        return;
    }
    int f = (blk - 1024 - NDE) * 256 + tid;
    if (f >= NDE * 2048) return;
    int de = f >> 11, i = f & 2047;
    int g = i >> 4, kf = (i >> 2) & 3, qq = i & 3;
    const float* W2g = W2 + (size_t)de * 16384;
    f32x4_t a  = *(const f32x4_t*)&W2g[g * 128 + kf * 32 + qq * 4];
    f32x4_t bb = *(const f32x4_t*)&W2g[g * 128 + kf * 32 + 16 + qq * 4];
    union { _Float16 hh[8]; half8_t v; } u;
    #pragma unroll
    for (int r = 0; r < 4; r++) { u.hh[r] = (_Float16)a[r]; u.hh[4 + r] = (_Float16)bb[r]; }
    *(half8_t*)&w2h[(size_t)de * 16384 + g * 128 + kf * 32 + qq * 8] = u.v;
}

// ---- fused 3-layer ensemble MLP, v2:
// One 1024-thread (16-wave) block per (de, half-batch). ALL weights live in a
// single LDS copy (W1 frags 16KB + W2 34KB + W3 4KB + b2) shared by 16 waves,
// instead of per-wave register copies (the old w1frag[8][2] = 64 VGPRs was
// quadruplicated per block and pushed live pressure to ~190 regs -> scratch
// spills: WRITE_SIZE 145MB vs 11MB of true output). Per-mt af loads keep the
// layer-2 working set at ~8 regs. Target: <=128 VGPR, zero spill, 16 waves/CU.
// XCD grouping: both chunk-blocks of a de land on the same XCD (bid%8).
template <bool PACKED>
__global__ __launch_bounds__(1024, 4) void mlp_kernel(
    const _Float16* __restrict__ x16,
    const float* __restrict__ W1, const float* __restrict__ b1,
    const float* __restrict__ W2, const float* __restrict__ b2,
    const float* __restrict__ W3, const float* __restrict__ b3,
    const _Float16* __restrict__ w1h, const _Float16* __restrict__ w2h,
    const _Float16* __restrict__ w3h,
    float* __restrict__ mean_t, float* __restrict__ logvar_t)
{
    __shared__ _Float16 w1s[8192];        // W1 A-fragments (b1 folded), 16 KB
    __shared__ _Float16 w2s[128 * 136];   // rows padded 128->136 halves, 34 KB
    __shared__ _Float16 w3s[2048];        // layer-3 A fragments, 4 KB
    __shared__ float    b2s[128];

    const int bid   = blockIdx.x;
    // bid = grp*16 + chunk*8 + xcd : both chunks of a de share an XCD's L2.
    const int grp   = bid >> 4;
    const int xcd   = bid & 7;
    const int chunk = (bid >> 3) & 1;
    const int de    = grp * 8 + xcd;
    if (de >= NDE) return;   // whole block exits together (no barrier hazard)

    const int tid  = threadIdx.x;
    const int wave = tid >> 6;
    const int lane = tid & 63;
    const int c    = lane & 15;
    const int q    = lane >> 4;

    // ---- stage W1 + W2 + W3 + b2 into LDS (one copy for all 16 waves)
    if constexpr (PACKED) {
        *(half8_t*)&w1s[tid * 8] = *(const half8_t*)&w1h[(size_t)de * 8192 + tid * 8];
        const _Float16* W2g = w2h + (size_t)de * 16384;
        #pragma unroll
        for (int i0 = 0; i0 < 2; i0++) {
            int i = tid + i0 * 1024;
            half8_t v = *(const half8_t*)&W2g[i * 8];
            *(half8_t*)&w2s[(i >> 4) * 136 + (i & 15) * 8] = v;
        }
        if (tid < 256)
            *(half8_t*)&w3s[tid * 8] = *(const half8_t*)&w3h[(size_t)de * 2048 + tid * 8];
    } else {
        // build W1 fragment layout from f32 (one frag-of-8 per thread)
        {
            const float* W1g = W1 + (size_t)de * (128 * 40);
            const float* b1g = b1 + (size_t)de * 128;
            int s = tid;
            int ht = s >> 7, rem = s & 127, kff = rem >> 6, ln = rem & 63;
            int cc = ln & 15, qq = ln >> 4, h = ht * 16 + cc;
            union { _Float16 hh[8]; half8_t v; } u;
            if (kff == 0) {
                f32x4_t a  = *(const f32x4_t*)&W1g[h * 40 + qq * 8];
                f32x4_t bb = *(const f32x4_t*)&W1g[h * 40 + qq * 8 + 4];
                #pragma unroll
                for (int r = 0; r < 4; r++) { u.hh[r] = (_Float16)a[r]; u.hh[4 + r] = (_Float16)bb[r]; }
            } else {
                #pragma unroll
                for (int r = 0; r < 8; r++) u.hh[r] = (_Float16)0.0f;
                if (qq == 0) {
                    f32x4_t a  = *(const f32x4_t*)&W1g[h * 40 + 32];
                    f32x4_t bb = *(const f32x4_t*)&W1g[h * 40 + 36];
                    #pragma unroll
                    for (int r = 0; r < 4; r++) { u.hh[r] = (_Float16)a[r]; u.hh[4 + r] = (_Float16)bb[r]; }
                } else if (qq == 1) {
                    u.hh[0] = (_Float16)b1g[h];
                }
            }
            *(half8_t*)&w1s[(ht * 2 + kff) * 512 + ln * 8] = u.v;
        }
        const float* W2g = W2 + (size_t)de * 16384;
        #pragma unroll
        for (int i0 = 0; i0 < 2; i0++) {
            int i = tid + i0 * 1024;
            int g  = i >> 4;
            int kf = (i >> 2) & 3;
            int qq = i & 3;
            f32x4_t a  = *(const f32x4_t*)&W2g[g * 128 + kf * 32 + qq * 4];
            f32x4_t bb = *(const f32x4_t*)&W2g[g * 128 + kf * 32 + 16 + qq * 4];
            union { _Float16 hh[8]; half8_t v; } u;
            #pragma unroll
            for (int r = 0; r < 4; r++) { u.hh[r] = (_Float16)a[r]; u.hh[4 + r] = (_Float16)bb[r]; }
            *(half8_t*)&w2s[g * 136 + kf * 32 + qq * 8] = u.v;
        }
        if (tid < 256) {
            const float* W3g = W3 + (size_t)de * 256;
            int kf = tid >> 6, ln = tid & 63, c2 = ln & 15, q2 = ln >> 4;
            union { _Float16 hh[8]; half8_t v; } u;
            #pragma unroll
            for (int r = 0; r < 8; r++) u.hh[r] = (_Float16)0.0f;
            if (c2 < 2) {
                #pragma unroll
                for (int r = 0; r < 4; r++) {
                    u.hh[r]     = (_Float16)W3g[c2 * 128 + kf * 32 + q2 * 4 + r];
                    u.hh[4 + r] = (_Float16)W3g[c2 * 128 + kf * 32 + 16 + q2 * 4 + r];
                }
            }
            *(half8_t*)&w3s[kf * 512 + ln * 8] = u.v;
        }
    }
    if (tid < 128) b2s[tid] = b2[de * 128 + tid];
    __syncthreads();

    const float b3m = b3[de * 2 + 0];
    const float b3l = b3[de * 2 + 1];
    const f32x4_t zero4 = {0.f, 0.f, 0.f, 0.f};
    f32x4_t c3init = zero4;
    if (q == 0) { c3init[0] = b3m; c3init[1] = b3l; }

    #pragma unroll 1
    for (int it = 0; it < 4; it++) {
        const int b0 = chunk * 2048 + it * 512 + wave * 32;

        half8_t xf[2][2];
        #pragma unroll
        for (int nt = 0; nt < 2; nt++)
            #pragma unroll
            for (int kf = 0; kf < 2; kf++)
                xf[nt][kf] = *(const half8_t*)&x16[(b0 + nt * 16 + c) * 64 + kf * 32 + q * 8];

        f32x4_t acc2[8][2];
        #pragma unroll
        for (int mt = 0; mt < 8; mt++) {
            f32x4_t binit = *(const f32x4_t*)&b2s[mt * 16 + q * 4];
            acc2[mt][0] = binit;
            acc2[mt][1] = binit;
        }

        // ---- interleaved layer1 -> layer2, one contraction chunk kf at a time.
        // unroll 1: each kf is a self-contained pipeline stage, keeps pressure low.
        #pragma unroll 1
        for (int kf = 0; kf < 4; kf++) {
            unsigned Pl[2][2][2];
            #pragma unroll
            for (int h2 = 0; h2 < 2; h2++) {
                const int ht = kf * 2 + h2;
                half8_t a0 = *(const half8_t*)&w1s[(ht * 2 + 0) * 512 + lane * 8];
                half8_t a1 = *(const half8_t*)&w1s[(ht * 2 + 1) * 512 + lane * 8];
                #pragma unroll
                for (int nt = 0; nt < 2; nt++) {
                    f32x4_t a = __builtin_amdgcn_mfma_f32_16x16x32_f16(a0, xf[nt][0], zero4, 0, 0, 0);
                    f32x4_t t = __builtin_amdgcn_mfma_f32_16x16x32_f16(a1, xf[nt][1], a, 0, 0, 0);
                    Pl[h2][nt][0] = __builtin_bit_cast(unsigned,
                        __builtin_amdgcn_cvt_pkrtz(fast_silu(t[0]), fast_silu(t[1])));
                    Pl[h2][nt][1] = __builtin_bit_cast(unsigned,
                        __builtin_amdgcn_cvt_pkrtz(fast_silu(t[2]), fast_silu(t[3])));
                }
            }
            union { unsigned u[4]; half8_t h; } bu0, bu1;
            bu0.u[0] = Pl[0][0][0]; bu0.u[1] = Pl[0][0][1];
            bu0.u[2] = Pl[1][0][0]; bu0.u[3] = Pl[1][0][1];
            bu1.u[0] = Pl[0][1][0]; bu1.u[1] = Pl[0][1][1];
            bu1.u[2] = Pl[1][1][0]; bu1.u[3] = Pl[1][1][1];
            #pragma unroll
            for (int mt = 0; mt < 8; mt++) {
                half8_t af = *(const half8_t*)&w2s[(mt * 16 + c) * 136 + kf * 32 + q * 8];
                acc2[mt][0] = __builtin_amdgcn_mfma_f32_16x16x32_f16(af, bu0.h, acc2[mt][0], 0, 0, 0);
                acc2[mt][1] = __builtin_amdgcn_mfma_f32_16x16x32_f16(af, bu1.h, acc2[mt][1], 0, 0, 0);
            }
        }

        // ---- interleaved layer2-silu -> layer3
        f32x4_t acc3[2] = {c3init, c3init};
        #pragma unroll
        for (int kf2 = 0; kf2 < 4; kf2++) {
            half8_t w3f = *(const half8_t*)&w3s[kf2 * 512 + lane * 8];
            #pragma unroll
            for (int nt = 0; nt < 2; nt++) {
                union { unsigned u[4]; half8_t h; } bu;
                #pragma unroll
                for (int h2 = 0; h2 < 2; h2++) {
                    const int mt = kf2 * 2 + h2;
                    bu.u[2 * h2 + 0] = __builtin_bit_cast(unsigned,
                        __builtin_amdgcn_cvt_pkrtz(fast_silu(acc2[mt][nt][0]), fast_silu(acc2[mt][nt][1])));
                    bu.u[2 * h2 + 1] = __builtin_bit_cast(unsigned,
                        __builtin_amdgcn_cvt_pkrtz(fast_silu(acc2[mt][nt][2]), fast_silu(acc2[mt][nt][3])));
                }
                acc3[nt] = __builtin_amdgcn_mfma_f32_16x16x32_f16(w3f, bu.h, acc3[nt], 0, 0, 0);
            }
        }

        #pragma unroll
        for (int nt = 0; nt < 2; nt++) {
            if (q == 0) {
                const int bg = b0 + nt * 16 + c;
                float vm = acc3[nt][0];
                float vl = acc3[nt][1];
                vl = 5.0f - fast_softplus(5.0f - vl);
                vl = -10.0f + fast_softplus(vl + 10.0f);
                mean_t[(size_t)de * 4096 + bg]   = vm;
                logvar_t[(size_t)de * 4096 + bg] = vl;
            }
        }
    }
}

// ---- [330][4096] -> [4096][330] transpose for both planes
__global__ __launch_bounds__(256) void transpose_out_kernel(
    const float* __restrict__ mean_t, const float* __restrict__ logvar_t,
    float* __restrict__ out)
{
    __shared__ float tile[32][33];
    const int bg0 = blockIdx.x * 32;
    const int de0 = blockIdx.y * 32;
    const float* src = blockIdx.z ? logvar_t : mean_t;
    float* dst = blockIdx.z ? (out + OUT_HALF) : out;
    const int cidx = threadIdx.x & 31;
    const int r0   = threadIdx.x >> 5;
    #pragma unroll
    for (int k = 0; k < 4; k++) {
        int de_l = r0 + k * 8;
        if (de0 + de_l < NDE)
            tile[de_l][cidx] = src[(size_t)(de0 + de_l) * 4096 + bg0 + cidx];
    }
    __syncthreads();
    #pragma unroll
    for (int k = 0; k < 4; k++) {
        int bg_l = r0 + k * 8;
        if (de0 + cidx < NDE)
            dst[(size_t)(bg0 + bg_l) * 330 + de0 + cidx] = tile[cidx][bg_l];
    }
}

extern "C" void kernel_launch(void* const* d_in, const int* in_sizes, int n_in,
                              void* d_out, int out_size, void* d_ws, size_t ws_size,
                              hipStream_t stream) {
    (void)in_sizes; (void)n_in; (void)out_size;
    const float* x  = (const float*)d_in[0];
    const float* W1 = (const float*)d_in[1];
    const float* b1 = (const float*)d_in[2];
    const float* W2 = (const float*)d_in[3];
    const float* b2 = (const float*)d_in[4];
    const float* W3 = (const float*)d_in[5];
    const float* b3 = (const float*)d_in[6];
    float* out = (float*)d_out;

    char* ws = (char*)d_ws;
    _Float16* x16   = (_Float16*)(ws + OFF_X16);
    float* mean_t   = (float*)(ws + OFF_MEANT);
    float* logvar_t = (float*)(ws + OFF_LOGVT);

    // 42 groups x 16 blocks: de = grp*8 + (bid&7), chunk = (bid>>3)&1
    const int MLP_GRID = 42 * 16;

    if (ws_size >= WS_PACKED_BYTES) {
        _Float16* w1h = (_Float16*)(ws + OFF_W1H);
        _Float16* w3h = (_Float16*)(ws + OFF_W3H);
        _Float16* w2h = (_Float16*)(ws + OFF_W2H);
        hipLaunchKernelGGL(prep_all_kernel, dim3(1024 + NDE + 2640), dim3(256), 0, stream,
                           x, W1, b1, W2, W3, x16, w1h, w2h, w3h);
        hipLaunchKernelGGL((mlp_kernel<true>), dim3(MLP_GRID), dim3(1024), 0, stream,
                           x16, W1, b1, W2, b2, W3, b3, w1h, w2h, w3h, mean_t, logvar_t);
    } else {
        hipLaunchKernelGGL(prep_x_kernel, dim3(1024), dim3(256), 0, stream, x, x16);
        hipLaunchKernelGGL((mlp_kernel<false>), dim3(MLP_GRID), dim3(1024), 0, stream,
                           x16, W1, b1, W2, b2, W3, b3, x16, x16, x16, mean_t, logvar_t);
    }
    hipLaunchKernelGGL(transpose_out_kernel, dim3(128, 11, 2), dim3(256), 0, stream,
                       mean_t, logvar_t, out);
}

// Round 2
// 213.878 us; speedup vs baseline: 1.5150x; 1.1347x over previous
//
#include <hip/hip_runtime.h>

typedef _Float16 half8_t __attribute__((ext_vector_type(8)));
typedef float    f32x4_t __attribute__((ext_vector_type(4)));

#define OUT_HALF 1351680   // 4096*330
#define NDE 330

// ws layout (bytes)
#define OFF_X16    0u
#define OFF_MEANT  524288u
#define OFF_LOGVT  5931008u
#define OFF_W1H    11337728u   // 330*8192 halves  (W1 frags, b1 folded)
#define OFF_W3H    16744448u   // 330*2048 halves  (W3 frags)
#define OFF_W2H    18096128u   // 330*16384 halves (W2 fragment-linear)
#define WS_PACKED_BYTES 28909568u

__device__ __forceinline__ float fast_silu(float x) {
    float e = __builtin_amdgcn_exp2f(x * -1.44269504f);
    return x * __builtin_amdgcn_rcpf(1.0f + e);
}

__device__ __forceinline__ float fast_softplus(float x) {
    float e = __builtin_amdgcn_exp2f(x * 1.44269504f);
    return __builtin_amdgcn_logf(1.0f + e) * 0.69314718f;
}

// ---- x prep only (fallback path)
__global__ __launch_bounds__(256) void prep_x_kernel(const float* __restrict__ x,
                                                     _Float16* __restrict__ x16) {
    int idx = blockIdx.x * 256 + threadIdx.x;
    if (idx >= 4096 * 64) return;
    int b = idx >> 6, cc = idx & 63;
    float v = (cc < 40) ? x[b * 40 + cc] : (cc == 40 ? 1.0f : 0.0f);
    x16[idx] = (_Float16)v;
}

// ---- combined prep: x16 + W1/W3 fragment pack + W2 fragment-linear pack
__global__ __launch_bounds__(256) void prep_all_kernel(
    const float* __restrict__ x,
    const float* __restrict__ W1, const float* __restrict__ b1,
    const float* __restrict__ W2, const float* __restrict__ W3,
    _Float16* __restrict__ x16, _Float16* __restrict__ w1h,
    _Float16* __restrict__ w2h, _Float16* __restrict__ w3h)
{
    const int blk = blockIdx.x;
    const int tid = threadIdx.x;
    if (blk < 1024) {
        int idx = blk * 256 + tid;
        int b = idx >> 6, cc = idx & 63;
        float v = (cc < 40) ? x[b * 40 + cc] : (cc == 40 ? 1.0f : 0.0f);
        x16[idx] = (_Float16)v;
        return;
    }
    if (blk < 1024 + NDE) {
        const int de = blk - 1024;
        const float* W1g = W1 + (size_t)de * (128 * 40);
        const float* b1g = b1 + (size_t)de * 128;
        const float* W3g = W3 + (size_t)de * 256;
        for (int s = tid; s < 1024; s += 256) {
            int ht = s >> 7, rem = s & 127, kf = rem >> 6, lane = rem & 63;
            int c = lane & 15, q = lane >> 4, h = ht * 16 + c;
            union { _Float16 hh[8]; half8_t v; } u;
            if (kf == 0) {
                f32x4_t a  = *(const f32x4_t*)&W1g[h * 40 + q * 8];
                f32x4_t bb = *(const f32x4_t*)&W1g[h * 40 + q * 8 + 4];
                #pragma unroll
                for (int r = 0; r < 4; r++) { u.hh[r] = (_Float16)a[r]; u.hh[4 + r] = (_Float16)bb[r]; }
            } else {
                #pragma unroll
                for (int r = 0; r < 8; r++) u.hh[r] = (_Float16)0.0f;
                if (q == 0) {
                    f32x4_t a  = *(const f32x4_t*)&W1g[h * 40 + 32];
                    f32x4_t bb = *(const f32x4_t*)&W1g[h * 40 + 36];
                    #pragma unroll
                    for (int r = 0; r < 4; r++) { u.hh[r] = (_Float16)a[r]; u.hh[4 + r] = (_Float16)bb[r]; }
                } else if (q == 1) {
                    u.hh[0] = (_Float16)b1g[h];
                }
            }
            *(half8_t*)&w1h[(size_t)de * 8192 + (ht * 2 + kf) * 512 + lane * 8] = u.v;
        }
        if (tid < 256) {
            int kf = tid >> 6, lane = tid & 63, c = lane & 15, q = lane >> 4;
            union { _Float16 hh[8]; half8_t v; } u;
            #pragma unroll
            for (int r = 0; r < 8; r++) u.hh[r] = (_Float16)0.0f;
            if (c < 2) {
                #pragma unroll
                for (int r = 0; r < 4; r++) {
                    u.hh[r]     = (_Float16)W3g[c * 128 + kf * 32 + q * 4 + r];
                    u.hh[4 + r] = (_Float16)W3g[c * 128 + kf * 32 + 16 + q * 4 + r];
                }
            }
            *(half8_t*)&w3h[(size_t)de * 2048 + kf * 512 + lane * 8] = u.v;
        }
        return;
    }
    // W2: pack to fragment-linear layout [mt*4+kf][q*16+c][8] so that the mlp
    // kernel's af read at (mt,kf,lane) is a lane-linear 16B LDS read (no bank
    // conflicts) and staging is a pure linear copy.
    int f = (blk - 1024 - NDE) * 256 + tid;
    if (f >= NDE * 2048) return;
    int de = f >> 11, i = f & 2047;
    int g = i >> 4, kf = (i >> 2) & 3, qq = i & 3;
    const float* W2g = W2 + (size_t)de * 16384;
    f32x4_t a  = *(const f32x4_t*)&W2g[g * 128 + kf * 32 + qq * 4];
    f32x4_t bb = *(const f32x4_t*)&W2g[g * 128 + kf * 32 + 16 + qq * 4];
    union { _Float16 hh[8]; half8_t v; } u;
    #pragma unroll
    for (int r = 0; r < 4; r++) { u.hh[r] = (_Float16)a[r]; u.hh[4 + r] = (_Float16)bb[r]; }
    int off = (((g >> 4) * 4 + kf) * 64 + qq * 16 + (g & 15)) * 8;
    *(half8_t*)&w2h[(size_t)de * 16384 + off] = u.v;
}

// ---- fused 3-layer ensemble MLP, v3:
// 512-thread (8-wave) blocks, one per (de, 512-row chunk); grid 42*64 with
// de = grp*8 + (bid&7) so all 8 chunks of a de hit the same XCD's L2.
// 2 blocks/CU resident (regs <= 128 total incl. AGPR acc, LDS 52.5KB) ->
// smooth ~5-round schedule instead of 3 uneven rounds of 1024-blocks.
// W2 LDS is fragment-linear: af reads are lane-linear 16B (conflict-free).
// Register shaves vs v2: Pl folded into bu (-8), c3init vector removed (-4,
// b3 added in epilogue from SGPRs) -> genuinely spill-free at the 128 cap.
template <bool PACKED>
__global__ __launch_bounds__(512, 4) void mlp_kernel(
    const _Float16* __restrict__ x16,
    const float* __restrict__ W1, const float* __restrict__ b1,
    const float* __restrict__ W2, const float* __restrict__ b2,
    const float* __restrict__ W3, const float* __restrict__ b3,
    const _Float16* __restrict__ w1h, const _Float16* __restrict__ w2h,
    const _Float16* __restrict__ w3h,
    float* __restrict__ mean_t, float* __restrict__ logvar_t)
{
    __shared__ _Float16 w1s[8192];        // W1 A-fragments (b1 folded), 16 KB
    __shared__ _Float16 w2s[16384];       // W2 fragment-linear, 32 KB
    __shared__ _Float16 w3s[2048];        // layer-3 A fragments, 4 KB
    __shared__ float    b2s[128];

    const int bid   = blockIdx.x;
    // bid = grp*64 + chunk*8 + xcd : all 8 chunks of a de share an XCD's L2.
    const int grp   = bid >> 6;
    const int xcd   = bid & 7;
    const int chunk = (bid >> 3) & 7;
    const int de    = grp * 8 + xcd;
    if (de >= NDE) return;   // whole block exits together (no barrier hazard)

    const int tid  = threadIdx.x;
    const int wave = tid >> 6;
    const int lane = tid & 63;
    const int c    = lane & 15;
    const int q    = lane >> 4;

    // ---- stage W1 + W2 + W3 + b2 into LDS (one copy for all 8 waves)
    if constexpr (PACKED) {
        const _Float16* W1g = w1h + (size_t)de * 8192;
        *(half8_t*)&w1s[tid * 8]         = *(const half8_t*)&W1g[tid * 8];
        *(half8_t*)&w1s[(tid + 512) * 8] = *(const half8_t*)&W1g[(tid + 512) * 8];
        const _Float16* W2g = w2h + (size_t)de * 16384;
        #pragma unroll
        for (int i0 = 0; i0 < 4; i0++) {
            int i = tid + i0 * 512;
            *(half8_t*)&w2s[i * 8] = *(const half8_t*)&W2g[i * 8];
        }
        if (tid < 256)
            *(half8_t*)&w3s[tid * 8] = *(const half8_t*)&w3h[(size_t)de * 2048 + tid * 8];
    } else {
        // build W1 fragment layout from f32 (two frag-of-8 per thread)
        {
            const float* W1g = W1 + (size_t)de * (128 * 40);
            const float* b1g = b1 + (size_t)de * 128;
            for (int s = tid; s < 1024; s += 512) {
                int ht = s >> 7, rem = s & 127, kff = rem >> 6, ln = rem & 63;
                int cc = ln & 15, qq = ln >> 4, h = ht * 16 + cc;
                union { _Float16 hh[8]; half8_t v; } u;
                if (kff == 0) {
                    f32x4_t a  = *(const f32x4_t*)&W1g[h * 40 + qq * 8];
                    f32x4_t bb = *(const f32x4_t*)&W1g[h * 40 + qq * 8 + 4];
                    #pragma unroll
                    for (int r = 0; r < 4; r++) { u.hh[r] = (_Float16)a[r]; u.hh[4 + r] = (_Float16)bb[r]; }
                } else {
                    #pragma unroll
                    for (int r = 0; r < 8; r++) u.hh[r] = (_Float16)0.0f;
                    if (qq == 0) {
                        f32x4_t a  = *(const f32x4_t*)&W1g[h * 40 + 32];
                        f32x4_t bb = *(const f32x4_t*)&W1g[h * 40 + 36];
                        #pragma unroll
                        for (int r = 0; r < 4; r++) { u.hh[r] = (_Float16)a[r]; u.hh[4 + r] = (_Float16)bb[r]; }
                    } else if (qq == 1) {
                        u.hh[0] = (_Float16)b1g[h];
                    }
                }
                *(half8_t*)&w1s[(ht * 2 + kff) * 512 + ln * 8] = u.v;
            }
        }
        const float* W2g = W2 + (size_t)de * 16384;
        #pragma unroll
        for (int i0 = 0; i0 < 4; i0++) {
            int i = tid + i0 * 512;         // fragment-linear index
            int F = i >> 6, l = i & 63;     // F = mt*4+kf
            int mt = F >> 2, kf = F & 3, q2 = l >> 4, c2 = l & 15;
            int g = mt * 16 + c2;
            f32x4_t a  = *(const f32x4_t*)&W2g[g * 128 + kf * 32 + q2 * 4];
            f32x4_t bb = *(const f32x4_t*)&W2g[g * 128 + kf * 32 + 16 + q2 * 4];
            union { _Float16 hh[8]; half8_t v; } u;
            #pragma unroll
            for (int r = 0; r < 4; r++) { u.hh[r] = (_Float16)a[r]; u.hh[4 + r] = (_Float16)bb[r]; }
            *(half8_t*)&w2s[i * 8] = u.v;
        }
        if (tid < 256) {
            const float* W3g = W3 + (size_t)de * 256;
            int kf = tid >> 6, ln = tid & 63, c2 = ln & 15, q2 = ln >> 4;
            union { _Float16 hh[8]; half8_t v; } u;
            #pragma unroll
            for (int r = 0; r < 8; r++) u.hh[r] = (_Float16)0.0f;
            if (c2 < 2) {
                #pragma unroll
                for (int r = 0; r < 4; r++) {
                    u.hh[r]     = (_Float16)W3g[c2 * 128 + kf * 32 + q2 * 4 + r];
                    u.hh[4 + r] = (_Float16)W3g[c2 * 128 + kf * 32 + 16 + q2 * 4 + r];
                }
            }
            *(half8_t*)&w3s[kf * 512 + ln * 8] = u.v;
        }
    }
    if (tid < 128) b2s[tid] = b2[de * 128 + tid];
    __syncthreads();

    const float b3m = b3[de * 2 + 0];   // uniform -> SGPRs
    const float b3l = b3[de * 2 + 1];
    const f32x4_t zero4 = {0.f, 0.f, 0.f, 0.f};

    #pragma unroll 1
    for (int it = 0; it < 2; it++) {
        const int b0 = chunk * 512 + it * 256 + wave * 32;

        half8_t xf[2][2];
        #pragma unroll
        for (int nt = 0; nt < 2; nt++)
            #pragma unroll
            for (int kf = 0; kf < 2; kf++)
                xf[nt][kf] = *(const half8_t*)&x16[(b0 + nt * 16 + c) * 64 + kf * 32 + q * 8];

        f32x4_t acc2[8][2];
        #pragma unroll
        for (int mt = 0; mt < 8; mt++) {
            f32x4_t binit = *(const f32x4_t*)&b2s[mt * 16 + q * 4];
            acc2[mt][0] = binit;
            acc2[mt][1] = binit;
        }

        // ---- interleaved layer1 -> layer2, one contraction chunk kf at a time.
        #pragma unroll 1
        for (int kf = 0; kf < 4; kf++) {
            union { unsigned u[4]; half8_t h; } bu0, bu1;
            #pragma unroll
            for (int h2 = 0; h2 < 2; h2++) {
                const int ht = kf * 2 + h2;
                half8_t a0 = *(const half8_t*)&w1s[(ht * 2 + 0) * 512 + lane * 8];
                half8_t a1 = *(const half8_t*)&w1s[(ht * 2 + 1) * 512 + lane * 8];
                {
                    f32x4_t a = __builtin_amdgcn_mfma_f32_16x16x32_f16(a0, xf[0][0], zero4, 0, 0, 0);
                    f32x4_t t = __builtin_amdgcn_mfma_f32_16x16x32_f16(a1, xf[0][1], a, 0, 0, 0);
                    bu0.u[2 * h2 + 0] = __builtin_bit_cast(unsigned,
                        __builtin_amdgcn_cvt_pkrtz(fast_silu(t[0]), fast_silu(t[1])));
                    bu0.u[2 * h2 + 1] = __builtin_bit_cast(unsigned,
                        __builtin_amdgcn_cvt_pkrtz(fast_silu(t[2]), fast_silu(t[3])));
                }
                {
                    f32x4_t a = __builtin_amdgcn_mfma_f32_16x16x32_f16(a0, xf[1][0], zero4, 0, 0, 0);
                    f32x4_t t = __builtin_amdgcn_mfma_f32_16x16x32_f16(a1, xf[1][1], a, 0, 0, 0);
                    bu1.u[2 * h2 + 0] = __builtin_bit_cast(unsigned,
                        __builtin_amdgcn_cvt_pkrtz(fast_silu(t[0]), fast_silu(t[1])));
                    bu1.u[2 * h2 + 1] = __builtin_bit_cast(unsigned,
                        __builtin_amdgcn_cvt_pkrtz(fast_silu(t[2]), fast_silu(t[3])));
                }
            }
            #pragma unroll
            for (int mt = 0; mt < 8; mt++) {
                half8_t af = *(const half8_t*)&w2s[(mt * 4 + kf) * 512 + lane * 8];
                acc2[mt][0] = __builtin_amdgcn_mfma_f32_16x16x32_f16(af, bu0.h, acc2[mt][0], 0, 0, 0);
                acc2[mt][1] = __builtin_amdgcn_mfma_f32_16x16x32_f16(af, bu1.h, acc2[mt][1], 0, 0, 0);
            }
        }

        // ---- interleaved layer2-silu -> layer3
        f32x4_t acc3[2] = {zero4, zero4};
        #pragma unroll
        for (int kf2 = 0; kf2 < 4; kf2++) {
            half8_t w3f = *(const half8_t*)&w3s[kf2 * 512 + lane * 8];
            #pragma unroll
            for (int nt = 0; nt < 2; nt++) {
                union { unsigned u[4]; half8_t h; } bu;
                #pragma unroll
                for (int h2 = 0; h2 < 2; h2++) {
                    const int mt = kf2 * 2 + h2;
                    bu.u[2 * h2 + 0] = __builtin_bit_cast(unsigned,
                        __builtin_amdgcn_cvt_pkrtz(fast_silu(acc2[mt][nt][0]), fast_silu(acc2[mt][nt][1])));
                    bu.u[2 * h2 + 1] = __builtin_bit_cast(unsigned,
                        __builtin_amdgcn_cvt_pkrtz(fast_silu(acc2[mt][nt][2]), fast_silu(acc2[mt][nt][3])));
                }
                acc3[nt] = __builtin_amdgcn_mfma_f32_16x16x32_f16(w3f, bu.h, acc3[nt], 0, 0, 0);
            }
        }

        if (q == 0) {
            #pragma unroll
            for (int nt = 0; nt < 2; nt++) {
                const int bg = b0 + nt * 16 + c;
                float vm = acc3[nt][0] + b3m;
                float vl = acc3[nt][1] + b3l;
                vl = 5.0f - fast_softplus(5.0f - vl);
                vl = -10.0f + fast_softplus(vl + 10.0f);
                mean_t[(size_t)de * 4096 + bg]   = vm;
                logvar_t[(size_t)de * 4096 + bg] = vl;
            }
        }
    }
}

// ---- [330][4096] -> [4096][330] transpose for both planes
__global__ __launch_bounds__(256) void transpose_out_kernel(
    const float* __restrict__ mean_t, const float* __restrict__ logvar_t,
    float* __restrict__ out)
{
    __shared__ float tile[32][33];
    const int bg0 = blockIdx.x * 32;
    const int de0 = blockIdx.y * 32;
    const float* src = blockIdx.z ? logvar_t : mean_t;
    float* dst = blockIdx.z ? (out + OUT_HALF) : out;
    const int cidx = threadIdx.x & 31;
    const int r0   = threadIdx.x >> 5;
    #pragma unroll
    for (int k = 0; k < 4; k++) {
        int de_l = r0 + k * 8;
        if (de0 + de_l < NDE)
            tile[de_l][cidx] = src[(size_t)(de0 + de_l) * 4096 + bg0 + cidx];
    }
    __syncthreads();
    #pragma unroll
    for (int k = 0; k < 4; k++) {
        int bg_l = r0 + k * 8;
        if (de0 + cidx < NDE)
            dst[(size_t)(bg0 + bg_l) * 330 + de0 + cidx] = tile[cidx][bg_l];
    }
}

extern "C" void kernel_launch(void* const* d_in, const int* in_sizes, int n_in,
                              void* d_out, int out_size, void* d_ws, size_t ws_size,
                              hipStream_t stream) {
    (void)in_sizes; (void)n_in; (void)out_size;
    const float* x  = (const float*)d_in[0];
    const float* W1 = (const float*)d_in[1];
    const float* b1 = (const float*)d_in[2];
    const float* W2 = (const float*)d_in[3];
    const float* b2 = (const float*)d_in[4];
    const float* W3 = (const float*)d_in[5];
    const float* b3 = (const float*)d_in[6];
    float* out = (float*)d_out;

    char* ws = (char*)d_ws;
    _Float16* x16   = (_Float16*)(ws + OFF_X16);
    float* mean_t   = (float*)(ws + OFF_MEANT);
    float* logvar_t = (float*)(ws + OFF_LOGVT);

    // 42 groups x 64 blocks: de = grp*8 + (bid&7), chunk = (bid>>3)&7
    const int MLP_GRID = 42 * 64;

    if (ws_size >= WS_PACKED_BYTES) {
        _Float16* w1h = (_Float16*)(ws + OFF_W1H);
        _Float16* w3h = (_Float16*)(ws + OFF_W3H);
        _Float16* w2h = (_Float16*)(ws + OFF_W2H);
        hipLaunchKernelGGL(prep_all_kernel, dim3(1024 + NDE + 2640), dim3(256), 0, stream,
                           x, W1, b1, W2, W3, x16, w1h, w2h, w3h);
        hipLaunchKernelGGL((mlp_kernel<true>), dim3(MLP_GRID), dim3(512), 0, stream,
                           x16, W1, b1, W2, b2, W3, b3, w1h, w2h, w3h, mean_t, logvar_t);
    } else {
        hipLaunchKernelGGL(prep_x_kernel, dim3(1024), dim3(256), 0, stream, x, x16);
        hipLaunchKernelGGL((mlp_kernel<false>), dim3(MLP_GRID), dim3(512), 0, stream,
                           x16, W1, b1, W2, b2, W3, b3, x16, x16, x16, mean_t, logvar_t);
    }
    hipLaunchKernelGGL(transpose_out_kernel, dim3(128, 11, 2), dim3(256), 0, stream,
                       mean_t, logvar_t, out);
}